// Round 7
// baseline (219.722 us; speedup 1.0000x reference)
//
#include <hip/hip_runtime.h>

#define LN_EPS 1e-5f

typedef __attribute__((ext_vector_type(4))) float f32x4;
typedef __attribute__((ext_vector_type(8))) short bf16x8;

__device__ inline float bf2f(ushort u) {
    union { unsigned u32; float f; } c; c.u32 = (unsigned)u << 16; return c.f;
}
__device__ inline ushort f2bf(float f) {
    union { float f; unsigned u; } c; c.f = f;
    unsigned r = c.u + 0x7FFF + ((c.u >> 16) & 1);   // round-to-nearest-even
    return (ushort)(r >> 16);
}

// ---------------------------------------------------------------------------
// Weights in FRAGMENT ORDER: flat index
//   (((kc*4 + wave)*2 + ks)*4 + ni)*512 + lane*8 + j
// holds logical W^T element (n, k):
//   n = wave*64 + ni*16 + (lane&15),  k = kc*64 + ks*32 + (lane>>4)*8 + j
//   logical(n,k) = k<256 ? Wl[k][n] : Wr[k-256][n]
// Each wave's MFMA B-fragment load = one coalesced 1KB global load (L2-hot).
// ---------------------------------------------------------------------------
__global__ __launch_bounds__(256) void convert_w2(
    const float* __restrict__ Wl0, const float* __restrict__ Wr0,
    const float* __restrict__ Wl1, const float* __restrict__ Wr1,
    ushort* __restrict__ Wf0, ushort* __restrict__ Wf1)
{
    const int idx = blockIdx.x * 256 + threadIdx.x;   // 0 .. 262143
    const int half = idx >> 17;
    const int local = idx & 131071;
    const int j    = local & 7;
    const int lane = (local >> 3) & 63;
    const int ni   = (local >> 9) & 3;
    const int ks   = (local >> 11) & 1;
    const int wv   = (local >> 12) & 3;
    const int kc   = local >> 14;
    const int n = wv * 64 + ni * 16 + (lane & 15);
    const int k = kc * 64 + ks * 32 + (lane >> 4) * 8 + j;
    const float* Wl = half ? Wl1 : Wl0;
    const float* Wr = half ? Wr1 : Wr0;
    const float v = (k < 256) ? Wl[k * 256 + n] : Wr[(k - 256) * 256 + n];
    (half ? Wf1 : Wf0)[local] = f2bf(v);
}

// ---------------------------------------------------------------------------
// Fully fused SAGE layer. Gather phase: block's edge indices staged to LDS
// first (no global-latency in the per-target chain); per target all FAN row
// loads issued via an explicit array (guaranteed pipelining), then summed in
// the same e-order as before (bit-identical numerics). acc init deferred to
// after the gather so its 64 VGPRs don't inflate gather-phase pressure.
// ---------------------------------------------------------------------------
template <int BM, int FAN, typename XT>
__global__ __launch_bounds__(256, 3) void fused_sage(
    const XT* __restrict__ X, const int* __restrict__ src,
    const int* __restrict__ tlid, const ushort* __restrict__ Wf,
    const float* __restrict__ bias, const float* __restrict__ g,
    const float* __restrict__ be, ushort* __restrict__ H,
    int M, int fan_rt)
{
    constexpr int MI = BM / 16;
    constexpr int TPW = BM / 4;           // targets per wave
    constexpr int FANC = (FAN > 0) ? FAN : 1;
    __shared__ ushort As[BM * 256];       // BM*512 bytes, swizzled image
    __shared__ float rS[4][BM];
    __shared__ float rQ[4][BM];
    __shared__ int tl[BM];
    __shared__ int sidx[BM * FANC];

    const int tid = threadIdx.x;
    const int wave = tid >> 6;
    const int lane = tid & 63;
    const int l15 = lane & 15;
    const int l4 = lane >> 4;
    const long row0 = (long)blockIdx.x * BM;
    const int col0 = wave * 64;
    const int fan = FAN > 0 ? FAN : fan_rt;
    const float inv_fan = 1.0f / (float)fan;

    if (tid < BM) {
        long rr = row0 + tid; if (rr >= M) rr = M - 1;
        tl[tid] = tlid[rr];
    }
    if constexpr (FAN > 0) {
        const long gmax = (long)M * FAN - 1;
        for (int i = tid; i < BM * FAN; i += 256) {
            long gi = row0 * FAN + i; if (gi > gmax) gi = gmax;
            sidx[i] = src[gi];
        }
    }
    __syncthreads();                                   // barrier 0

    // ---- gather + mean -> As (k<256 half), swizzled ----
    for (int tg = wave * TPW; tg < wave * TPW + TPW; ++tg) {
        float a0 = 0.f, a1 = 0.f, a2 = 0.f, a3 = 0.f;
        if constexpr (FAN > 0) {
            if constexpr (sizeof(XT) == 4) {
                float4 v[FAN];
#pragma unroll
                for (int e = 0; e < FAN; ++e) {
                    const long s = (long)sidx[tg * FAN + e];
                    v[e] = *(const float4*)((const float*)X + s * 256 + lane * 4);
                }
#pragma unroll
                for (int e = 0; e < FAN; ++e) {
                    a0 += v[e].x; a1 += v[e].y; a2 += v[e].z; a3 += v[e].w;
                }
            } else {
                ushort4 v[FAN];
#pragma unroll
                for (int e = 0; e < FAN; ++e) {
                    const long s = (long)sidx[tg * FAN + e];
                    v[e] = *(const ushort4*)((const ushort*)X + s * 256 + lane * 4);
                }
#pragma unroll
                for (int e = 0; e < FAN; ++e) {
                    a0 += bf2f(v[e].x); a1 += bf2f(v[e].y);
                    a2 += bf2f(v[e].z); a3 += bf2f(v[e].w);
                }
            }
        } else {
            long t = row0 + tg; if (t >= M) t = M - 1;
            int myidx = 0;
            if (lane < fan) myidx = src[t * (long)fan + lane];
            for (int e = 0; e < fan; ++e) {
                const long s = (long)__shfl(myidx, e, 64);
                if constexpr (sizeof(XT) == 4) {
                    const float4 v = *(const float4*)((const float*)X + s * 256 + lane * 4);
                    a0 += v.x; a1 += v.y; a2 += v.z; a3 += v.w;
                } else {
                    const ushort4 v = *(const ushort4*)((const ushort*)X + s * 256 + lane * 4);
                    a0 += bf2f(v.x); a1 += bf2f(v.y); a2 += bf2f(v.z); a3 += bf2f(v.w);
                }
            }
        }

        ushort4 o;
        o.x = f2bf(a0 * inv_fan); o.y = f2bf(a1 * inv_fan);
        o.z = f2bf(a2 * inv_fan); o.w = f2bf(a3 * inv_fan);
        const int c = lane * 4;
        const int byte = tg * 512 + (c & ~63) * 2 + (((c & 63) * 2) ^ ((tg & 7) << 4));
        *(ushort4*)((char*)As + byte) = o;
    }
    __syncthreads();                                   // barrier 1

    // acc init deferred here (keeps gather-phase VGPR pressure low).
    f32x4 acc[MI][4];
#pragma unroll
    for (int mi = 0; mi < MI; ++mi)
#pragma unroll
        for (int ni = 0; ni < 4; ++ni)
            acc[mi][ni] = (f32x4){0.f, 0.f, 0.f, 0.f};

    // B-fragment load: one coalesced 16B/lane global load (L2-resident).
    auto ldfrag = [&](int kc, int q /*= ks*4+ni*/) -> bf16x8 {
        return *(const bf16x8*)(Wf + (((((kc << 2) + wave) << 1) + (q >> 2)) * 4
                                      + (q & 3)) * 512 + lane * 8);
    };
    auto mfma_chunk = [&](int kc, const bf16x8* bfr /*8: ks*4+ni*/) {
#pragma unroll
        for (int ks = 0; ks < 2; ++ks) {
            bf16x8 afr[MI];
#pragma unroll
            for (int mi = 0; mi < MI; ++mi) {
                const int r = mi * 16 + l15;
                const int byte = r * 512 + kc * 128 +
                                 ((ks * 64 + l4 * 16) ^ ((r & 7) << 4));
                afr[mi] = *(const bf16x8*)((const char*)As + byte);
            }
#pragma unroll
            for (int mi = 0; mi < MI; ++mi)
#pragma unroll
                for (int ni = 0; ni < 4; ++ni)
                    acc[mi][ni] = __builtin_amdgcn_mfma_f32_16x16x32_bf16(
                        afr[mi], bfr[ks * 4 + ni], acc[mi][ni], 0, 0, 0);
        }
    };

    // ---- MFMA chunks 0..3 ----
#pragma unroll
    for (int kc = 0; kc < 4; ++kc) {
        bf16x8 bfr[8];
#pragma unroll
        for (int q = 0; q < 8; ++q) bfr[q] = ldfrag(kc, q);
        mfma_chunk(kc, bfr);
    }
    __syncthreads();                                   // barrier 2

    // ---- overwrite As with x_tgt rows (k>=256 half), swizzled ----
    if constexpr (sizeof(XT) == 4) {
#pragma unroll
        for (int it = 0; it < BM / 4; ++it) {
            const int idx = tid + it * 256;
            const int r = idx >> 6, c4 = (idx & 63) * 4;
            const float4 v = *(const float4*)&(
                (const float*)X)[(size_t)tl[r] * 256 + c4];
            ushort4 o;
            o.x = f2bf(v.x); o.y = f2bf(v.y); o.z = f2bf(v.z); o.w = f2bf(v.w);
            const int byte = r * 512 + (c4 & ~63) * 2 + (((c4 & 63) * 2) ^ ((r & 7) << 4));
            *(ushort4*)((char*)As + byte) = o;
        }
    } else {
#pragma unroll
        for (int it = 0; it < BM / 8; ++it) {
            const int idx = tid + it * 256;
            const int r = idx >> 5, c = (idx & 31) * 8;
            const int4 v = *(const int4*)&(
                (const ushort*)X)[(size_t)tl[r] * 256 + c];
            const int byte = r * 512 + (c & ~63) * 2 + (((c & 63) * 2) ^ ((r & 7) << 4));
            *(int4*)((char*)As + byte) = v;
        }
    }
    __syncthreads();                                   // barrier 3

    // ---- MFMA chunks 4..7 ----
#pragma unroll
    for (int kc = 0; kc < 4; ++kc) {
        bf16x8 bfr[8];
#pragma unroll
        for (int q = 0; q < 8; ++q) bfr[q] = ldfrag(kc + 4, q);
        mfma_chunk(kc, bfr);
    }

    // ---- epilogue: bias, LN stats, normalize, ReLU, bf16 store ----
    float bj[4], gj[4], bej[4];
#pragma unroll
    for (int ni = 0; ni < 4; ++ni) {
        const int c = col0 + ni * 16 + l15;
        bj[ni] = bias[c]; gj[ni] = g[c]; bej[ni] = be[c];
    }

#pragma unroll
    for (int mi = 0; mi < MI; ++mi) {
#pragma unroll
        for (int r = 0; r < 4; ++r) {
            float s = 0.f, q = 0.f;
#pragma unroll
            for (int ni = 0; ni < 4; ++ni) {
                const float v = acc[mi][ni][r] + bj[ni];
                acc[mi][ni][r] = v;
                s += v; q += v * v;
            }
#pragma unroll
            for (int off = 1; off < 16; off <<= 1) {
                s += __shfl_xor(s, off, 64);
                q += __shfl_xor(q, off, 64);
            }
            if (l15 == 0) {
                const int m = mi * 16 + l4 * 4 + r;
                rS[wave][m] = s; rQ[wave][m] = q;
            }
        }
    }
    __syncthreads();                                   // barrier 4

#pragma unroll
    for (int mi = 0; mi < MI; ++mi) {
#pragma unroll
        for (int r = 0; r < 4; ++r) {
            const int m = mi * 16 + l4 * 4 + r;
            if (row0 + m >= M) continue;
            const float s = rS[0][m] + rS[1][m] + rS[2][m] + rS[3][m];
            const float q = rQ[0][m] + rQ[1][m] + rQ[2][m] + rQ[3][m];
            const float mu = s * (1.f / 256.f);
            const float var = q * (1.f / 256.f) - mu * mu;
            const float inv = rsqrtf(var + LN_EPS);
#pragma unroll
            for (int ni = 0; ni < 4; ++ni) {
                float hn = (acc[mi][ni][r] - mu) * inv * gj[ni] + bej[ni];
                hn = fmaxf(hn, 0.f);
                H[(row0 + m) * 256 + col0 + ni * 16 + l15] = f2bf(hn);
            }
        }
    }
}

// ---------------------------------------------------------------------------
// Final FC: out[M,C] = H @ W + b. H bf16, W/b/out f32. Thread per column.
// ---------------------------------------------------------------------------
template <int RB>
__global__ __launch_bounds__(256) void fc_kernel_bf(
    const ushort* __restrict__ Hh, const float* __restrict__ W,
    const float* __restrict__ bias, float* __restrict__ out,
    int M, int C)
{
    const int j = threadIdx.x;
    const long row0 = (long)blockIdx.x * RB;
    if (j >= C) return;

    float acc[RB];
    const float bjv = bias[j];
#pragma unroll
    for (int r = 0; r < RB; ++r) acc[r] = bjv;

    const ushort* Hb = Hh + row0 * 256;
#pragma unroll 4
    for (int k = 0; k < 256; ++k) {
        const float w = W[(long)k * C + j];
#pragma unroll
        for (int r = 0; r < RB; ++r)
            acc[r] = fmaf(bf2f(Hb[r * 256 + k]), w, acc[r]);
    }
#pragma unroll
    for (int r = 0; r < RB; ++r)
        if (row0 + r < M) out[(row0 + r) * C + j] = acc[r];
}

// ---------------------------------------------------------------------------
// Launch
// ---------------------------------------------------------------------------
extern "C" void kernel_launch(void* const* d_in, const int* in_sizes, int n_in,
                              void* d_out, int out_size, void* d_ws, size_t ws_size,
                              hipStream_t stream)
{
    const float* x_feat = (const float*)d_in[0];
    const int*   e0src  = (const int*)d_in[1];
    const int*   tlid0  = (const int*)d_in[3];
    const int*   e1src  = (const int*)d_in[4];
    const int*   tlid1  = (const int*)d_in[6];
    const float* Wl0 = (const float*)d_in[7];
    const float* Wr0 = (const float*)d_in[8];
    const float* b0  = (const float*)d_in[9];
    const float* g0  = (const float*)d_in[10];
    const float* be0 = (const float*)d_in[11];
    const float* Wl1 = (const float*)d_in[12];
    const float* Wr1 = (const float*)d_in[13];
    const float* b1  = (const float*)d_in[14];
    const float* g1  = (const float*)d_in[15];
    const float* be1 = (const float*)d_in[16];
    const float* fcW = (const float*)d_in[17];
    const float* fcb = (const float*)d_in[18];

    const int N1   = in_sizes[3];
    const int fan0 = in_sizes[1] / N1;
    const int N2   = in_sizes[6];
    const int fan1 = in_sizes[4] / N2;
    const int C    = in_sizes[18];

    // Workspace: Wf0/Wf1 fragment-ordered bf16 (256 KB each), H0, H1.
    char* ws = (char*)d_ws;
    ushort* Wf0 = (ushort*)ws;                         ws += 256 * 512 * 2;
    ushort* Wf1 = (ushort*)ws;                         ws += 256 * 512 * 2;
    ushort* H0  = (ushort*)ws;                         ws += (size_t)N1 * 256 * 2;
    ushort* H1  = (ushort*)ws;

    convert_w2<<<1024, 256, 0, stream>>>(Wl0, Wr0, Wl1, Wr1, Wf0, Wf1);

    // ---- Layer 0 (fused gather+GEMM+LN+ReLU) ----
    if (fan0 == 15)
        fused_sage<64, 15, float><<<(N1 + 63) / 64, 256, 0, stream>>>(
            x_feat, e0src, tlid0, Wf0, b0, g0, be0, H0, N1, fan0);
    else
        fused_sage<64, 0, float><<<(N1 + 63) / 64, 256, 0, stream>>>(
            x_feat, e0src, tlid0, Wf0, b0, g0, be0, H0, N1, fan0);

    // ---- Layer 1 (fused) ----
    if (fan1 == 10)
        fused_sage<32, 10, ushort><<<(N2 + 31) / 32, 256, 0, stream>>>(
            H0, e1src, tlid1, Wf1, b1, g1, be1, H1, N2, fan1);
    else
        fused_sage<32, 0, ushort><<<(N2 + 31) / 32, 256, 0, stream>>>(
            H0, e1src, tlid1, Wf1, b1, g1, be1, H1, N2, fan1);

    // ---- FC ----
    fc_kernel_bf<16><<<(N2 + 15) / 16, 256, 0, stream>>>(
        H1, fcW, fcb, (float*)d_out, N2, C);
}

// Round 8
// 166.246 us; speedup vs baseline: 1.3217x; 1.3217x over previous
//
#include <hip/hip_runtime.h>

#define LN_EPS 1e-5f

typedef __attribute__((ext_vector_type(4))) float f32x4;
typedef __attribute__((ext_vector_type(8))) short bf16x8;

__device__ inline float bf2f(ushort u) {
    union { unsigned u32; float f; } c; c.u32 = (unsigned)u << 16; return c.f;
}
__device__ inline ushort f2bf(float f) {
    union { float f; unsigned u; } c; c.f = f;
    unsigned r = c.u + 0x7FFF + ((c.u >> 16) & 1);   // round-to-nearest-even
    return (ushort)(r >> 16);
}

// ---------------------------------------------------------------------------
// Weight conversion.
// Wf0/Wf1 in FRAGMENT ORDER: flat index
//   (((kc*4 + wave)*2 + ks)*4 + ni)*512 + lane*8 + j
// holds logical W^T element (n, k):
//   n = wave*64 + ni*16 + (lane&15),  k = kc*64 + ks*32 + (lane>>4)*8 + j
//   logical(n,k) = k<256 ? Wl[k][n] : Wr[k-256][n]
// Wfc (fc weights, N padded to 160) flat index
//   (((kc*2 + ks)*10 + ni)*512) + lane*8 + j
//   n = ni*16 + (lane&15), k = kc*64 + ks*32 + (lane>>4)*8 + j
//   value = n < C ? fcW[k*C + n] : 0
// ---------------------------------------------------------------------------
__global__ __launch_bounds__(256) void convert_w3(
    const float* __restrict__ Wl0, const float* __restrict__ Wr0,
    const float* __restrict__ Wl1, const float* __restrict__ Wr1,
    const float* __restrict__ fcW, int C,
    ushort* __restrict__ Wf0, ushort* __restrict__ Wf1,
    ushort* __restrict__ Wfc)
{
    const int idx = blockIdx.x * 256 + threadIdx.x;
    if (idx < 262144) {
        const int half = idx >> 17;
        const int local = idx & 131071;
        const int j    = local & 7;
        const int lane = (local >> 3) & 63;
        const int ni   = (local >> 9) & 3;
        const int ks   = (local >> 11) & 1;
        const int wv   = (local >> 12) & 3;
        const int kc   = local >> 14;
        const int n = wv * 64 + ni * 16 + (lane & 15);
        const int k = kc * 64 + ks * 32 + (lane >> 4) * 8 + j;
        const float* Wl = half ? Wl1 : Wl0;
        const float* Wr = half ? Wr1 : Wr0;
        const float v = (k < 256) ? Wl[k * 256 + n] : Wr[(k - 256) * 256 + n];
        (half ? Wf1 : Wf0)[local] = f2bf(v);
    } else if (idx < 262144 + 40960) {
        const int local = idx - 262144;
        const int j    = local & 7;
        const int lane = (local >> 3) & 63;
        const int f    = local >> 9;        // (kc*2+ks)*10 + ni
        const int ni   = f % 10;
        const int kcks = f / 10;
        const int ks   = kcks & 1;
        const int kc   = kcks >> 1;
        const int n = ni * 16 + (lane & 15);
        const int k = kc * 64 + ks * 32 + (lane >> 4) * 8 + j;
        const float v = (n < C) ? fcW[k * C + n] : 0.f;
        Wfc[local] = f2bf(v);
    }
}

// ---------------------------------------------------------------------------
// Fully fused SAGE layer (R6 structure):
//   gather+mean -> swizzled LDS A-tile (k<256)  | 1 barrier
//   MFMA chunks 0..3 (B-frags straight from L2) | no barriers
//   barrier; overwrite A-tile with x_tgt rows; barrier
//   MFMA chunks 4..7; bias+LN+ReLU epilogue.
// FC=false: write bf16 H.
// FC=true : re-stage relu_h into As (swizzled), barrier, second MFMA GEMM
//           against Wfc, write f32 out[M, C] directly (no H round-trip).
// ---------------------------------------------------------------------------
template <int BM, int FAN, typename XT, bool FC>
__global__ __launch_bounds__(256, 3) void fused_sage(
    const XT* __restrict__ X, const int* __restrict__ src,
    const int* __restrict__ tlid, const ushort* __restrict__ Wf,
    const float* __restrict__ bias, const float* __restrict__ g,
    const float* __restrict__ be, ushort* __restrict__ H,
    int M, int fan_rt,
    const ushort* __restrict__ Wfc, const float* __restrict__ fcb,
    float* __restrict__ out, int C)
{
    constexpr int MI = BM / 16;
    constexpr int TPW = BM / 4;      // targets per wave
    __shared__ ushort As[BM * 256];  // BM*512 bytes, swizzled image
    __shared__ float rS[4][BM];
    __shared__ float rQ[4][BM];
    __shared__ int tl[BM];

    const int tid = threadIdx.x;
    const int wave = tid >> 6;
    const int lane = tid & 63;
    const int l15 = lane & 15;
    const int l4 = lane >> 4;
    const long row0 = (long)blockIdx.x * BM;
    const int col0 = wave * 64;
    const int fan = FAN > 0 ? FAN : fan_rt;
    const float inv_fan = 1.0f / (float)fan;

    if (tid < BM) {
        long rr = row0 + tid; if (rr >= M) rr = M - 1;
        tl[tid] = tlid[rr];
    }

    // ---- gather + mean -> As (k<256 half), swizzled ----
    for (int tg = wave * TPW; tg < wave * TPW + TPW; ++tg) {
        long t = row0 + tg; if (t >= M) t = M - 1;
        int myidx = 0;
        if (lane < fan) myidx = src[t * (long)fan + lane];

        float a0 = 0.f, a1 = 0.f, a2 = 0.f, a3 = 0.f;
        auto body = [&](int e) {
            const long s = (long)__shfl(myidx, e, 64);
            if constexpr (sizeof(XT) == 4) {
                const float4 v = *(const float4*)((const float*)X + s * 256 + lane * 4);
                a0 += v.x; a1 += v.y; a2 += v.z; a3 += v.w;
            } else {
                const ushort4 v = *(const ushort4*)((const ushort*)X + s * 256 + lane * 4);
                a0 += bf2f(v.x); a1 += bf2f(v.y); a2 += bf2f(v.z); a3 += bf2f(v.w);
            }
        };
        if constexpr (FAN > 0) {
#pragma unroll
            for (int e = 0; e < FAN; ++e) body(e);
        } else {
            for (int e = 0; e < fan; ++e) body(e);
        }

        ushort4 o;
        o.x = f2bf(a0 * inv_fan); o.y = f2bf(a1 * inv_fan);
        o.z = f2bf(a2 * inv_fan); o.w = f2bf(a3 * inv_fan);
        const int c = lane * 4;
        const int byte = tg * 512 + (c & ~63) * 2 + (((c & 63) * 2) ^ ((tg & 7) << 4));
        *(ushort4*)((char*)As + byte) = o;
    }
    __syncthreads();                                   // barrier 1

    // acc init deferred (keeps gather-phase VGPR pressure low).
    f32x4 acc[MI][4];
#pragma unroll
    for (int mi = 0; mi < MI; ++mi)
#pragma unroll
        for (int ni = 0; ni < 4; ++ni)
            acc[mi][ni] = (f32x4){0.f, 0.f, 0.f, 0.f};

    // B-fragment load: one coalesced 16B/lane global load (L2-resident).
    auto ldfrag = [&](int kc, int q /*= ks*4+ni*/) -> bf16x8 {
        return *(const bf16x8*)(Wf + (((((kc << 2) + wave) << 1) + (q >> 2)) * 4
                                      + (q & 3)) * 512 + lane * 8);
    };
    auto mfma_chunk = [&](int kc, const bf16x8* bfr /*8: ks*4+ni*/) {
#pragma unroll
        for (int ks = 0; ks < 2; ++ks) {
            bf16x8 afr[MI];
#pragma unroll
            for (int mi = 0; mi < MI; ++mi) {
                const int r = mi * 16 + l15;
                const int byte = r * 512 + kc * 128 +
                                 ((ks * 64 + l4 * 16) ^ ((r & 7) << 4));
                afr[mi] = *(const bf16x8*)((const char*)As + byte);
            }
#pragma unroll
            for (int mi = 0; mi < MI; ++mi)
#pragma unroll
                for (int ni = 0; ni < 4; ++ni)
                    acc[mi][ni] = __builtin_amdgcn_mfma_f32_16x16x32_bf16(
                        afr[mi], bfr[ks * 4 + ni], acc[mi][ni], 0, 0, 0);
        }
    };

    // ---- MFMA chunks 0..3 ----
#pragma unroll
    for (int kc = 0; kc < 4; ++kc) {
        bf16x8 bfr[8];
#pragma unroll
        for (int q = 0; q < 8; ++q) bfr[q] = ldfrag(kc, q);
        mfma_chunk(kc, bfr);
    }
    __syncthreads();                                   // barrier 2

    // ---- overwrite As with x_tgt rows (k>=256 half), swizzled ----
    if constexpr (sizeof(XT) == 4) {
#pragma unroll
        for (int it = 0; it < BM / 4; ++it) {
            const int idx = tid + it * 256;
            const int r = idx >> 6, c4 = (idx & 63) * 4;
            const float4 v = *(const float4*)&(
                (const float*)X)[(size_t)tl[r] * 256 + c4];
            ushort4 o;
            o.x = f2bf(v.x); o.y = f2bf(v.y); o.z = f2bf(v.z); o.w = f2bf(v.w);
            const int byte = r * 512 + (c4 & ~63) * 2 + (((c4 & 63) * 2) ^ ((r & 7) << 4));
            *(ushort4*)((char*)As + byte) = o;
        }
    } else {
#pragma unroll
        for (int it = 0; it < BM / 8; ++it) {
            const int idx = tid + it * 256;
            const int r = idx >> 5, c = (idx & 31) * 8;
            const int4 v = *(const int4*)&(
                (const ushort*)X)[(size_t)tl[r] * 256 + c];
            const int byte = r * 512 + (c & ~63) * 2 + (((c & 63) * 2) ^ ((r & 7) << 4));
            *(int4*)((char*)As + byte) = v;
        }
    }
    __syncthreads();                                   // barrier 3

    // ---- MFMA chunks 4..7 ----
#pragma unroll
    for (int kc = 0; kc < 4; ++kc) {
        bf16x8 bfr[8];
#pragma unroll
        for (int q = 0; q < 8; ++q) bfr[q] = ldfrag(kc + 4, q);
        mfma_chunk(kc, bfr);
    }

    // ---- epilogue: bias, LN stats ----
    float bj[4], gj[4], bej[4];
#pragma unroll
    for (int ni = 0; ni < 4; ++ni) {
        const int c = col0 + ni * 16 + l15;
        bj[ni] = bias[c]; gj[ni] = g[c]; bej[ni] = be[c];
    }

#pragma unroll
    for (int mi = 0; mi < MI; ++mi) {
#pragma unroll
        for (int r = 0; r < 4; ++r) {
            float s = 0.f, q = 0.f;
#pragma unroll
            for (int ni = 0; ni < 4; ++ni) {
                const float v = acc[mi][ni][r] + bj[ni];
                acc[mi][ni][r] = v;
                s += v; q += v * v;
            }
#pragma unroll
            for (int off = 1; off < 16; off <<= 1) {
                s += __shfl_xor(s, off, 64);
                q += __shfl_xor(q, off, 64);
            }
            if (l15 == 0) {
                const int m = mi * 16 + l4 * 4 + r;
                rS[wave][m] = s; rQ[wave][m] = q;
            }
        }
    }
    __syncthreads();                                   // barrier 4

    // normalize + ReLU; write to H (FC=false) or back into As (FC=true)
#pragma unroll
    for (int mi = 0; mi < MI; ++mi) {
#pragma unroll
        for (int r = 0; r < 4; ++r) {
            const int m = mi * 16 + l4 * 4 + r;
            if (!FC && row0 + m >= M) continue;
            const float s = rS[0][m] + rS[1][m] + rS[2][m] + rS[3][m];
            const float q = rQ[0][m] + rQ[1][m] + rQ[2][m] + rQ[3][m];
            const float mu = s * (1.f / 256.f);
            const float var = q * (1.f / 256.f) - mu * mu;
            const float inv = rsqrtf(var + LN_EPS);
#pragma unroll
            for (int ni = 0; ni < 4; ++ni) {
                float hn = (acc[mi][ni][r] - mu) * inv * gj[ni] + bej[ni];
                hn = fmaxf(hn, 0.f);
                if constexpr (FC) {
                    const int cb = col0 + ni * 16 + l15;
                    const int byte = m * 512 + (cb & ~63) * 2 +
                                     (((cb & 63) * 2) ^ ((m & 7) << 4));
                    *(ushort*)((char*)As + byte) = f2bf(hn);
                } else {
                    H[(row0 + m) * 256 + col0 + ni * 16 + l15] = f2bf(hn);
                }
            }
        }
    }

    if constexpr (FC) {
        __syncthreads();                               // barrier 5

        // fc GEMM: out[BM x C] = relu_h @ fcW + fcb.
        // Wave w handles ni ∈ {w, w+4, w+8} (∩ [0,10)).
        f32x4 acc2[3][MI];
#pragma unroll
        for (int t = 0; t < 3; ++t)
#pragma unroll
            for (int mi = 0; mi < MI; ++mi)
                acc2[t][mi] = (f32x4){0.f, 0.f, 0.f, 0.f};

#pragma unroll
        for (int kc = 0; kc < 4; ++kc) {
#pragma unroll
            for (int ks = 0; ks < 2; ++ks) {
                bf16x8 afr[MI];
#pragma unroll
                for (int mi = 0; mi < MI; ++mi) {
                    const int r = mi * 16 + l15;
                    const int byte = r * 512 + kc * 128 +
                                     ((ks * 64 + l4 * 16) ^ ((r & 7) << 4));
                    afr[mi] = *(const bf16x8*)((const char*)As + byte);
                }
#pragma unroll
                for (int t = 0; t < 3; ++t) {
                    const int ni = wave + 4 * t;
                    if (ni < 10) {
                        const bf16x8 bfr = *(const bf16x8*)(
                            Wfc + (((kc * 2 + ks) * 10 + ni) << 9) + lane * 8);
#pragma unroll
                        for (int mi = 0; mi < MI; ++mi)
                            acc2[t][mi] = __builtin_amdgcn_mfma_f32_16x16x32_bf16(
                                afr[mi], bfr, acc2[t][mi], 0, 0, 0);
                    }
                }
            }
        }

#pragma unroll
        for (int t = 0; t < 3; ++t) {
            const int ni = wave + 4 * t;
            if (ni >= 10) continue;
            const int col = ni * 16 + l15;
            const float fb = (col < C) ? fcb[col] : 0.f;
#pragma unroll
            for (int mi = 0; mi < MI; ++mi)
#pragma unroll
                for (int r = 0; r < 4; ++r) {
                    const long row = row0 + mi * 16 + l4 * 4 + r;
                    if (col < C && row < M)
                        out[row * C + col] = acc2[t][mi][r] + fb;
                }
        }
    }
}

// ---------------------------------------------------------------------------
// Launch
// ---------------------------------------------------------------------------
extern "C" void kernel_launch(void* const* d_in, const int* in_sizes, int n_in,
                              void* d_out, int out_size, void* d_ws, size_t ws_size,
                              hipStream_t stream)
{
    const float* x_feat = (const float*)d_in[0];
    const int*   e0src  = (const int*)d_in[1];
    const int*   tlid0  = (const int*)d_in[3];
    const int*   e1src  = (const int*)d_in[4];
    const int*   tlid1  = (const int*)d_in[6];
    const float* Wl0 = (const float*)d_in[7];
    const float* Wr0 = (const float*)d_in[8];
    const float* b0  = (const float*)d_in[9];
    const float* g0  = (const float*)d_in[10];
    const float* be0 = (const float*)d_in[11];
    const float* Wl1 = (const float*)d_in[12];
    const float* Wr1 = (const float*)d_in[13];
    const float* b1  = (const float*)d_in[14];
    const float* g1  = (const float*)d_in[15];
    const float* be1 = (const float*)d_in[16];
    const float* fcW = (const float*)d_in[17];
    const float* fcb = (const float*)d_in[18];

    const int N1   = in_sizes[3];
    const int fan0 = in_sizes[1] / N1;
    const int N2   = in_sizes[6];
    const int fan1 = in_sizes[4] / N2;
    const int C    = in_sizes[18];

    // Workspace: Wf0/Wf1 (256 KB each), Wfc (80 KB), H0 (23.1 MB).
    char* ws = (char*)d_ws;
    ushort* Wf0 = (ushort*)ws;                         ws += 256 * 512 * 2;
    ushort* Wf1 = (ushort*)ws;                         ws += 256 * 512 * 2;
    ushort* Wfc = (ushort*)ws;                         ws += 160 * 256 * 2;
    ushort* H0  = (ushort*)ws;

    convert_w3<<<1184, 256, 0, stream>>>(Wl0, Wr0, Wl1, Wr1, fcW, C,
                                         Wf0, Wf1, Wfc);

    // ---- Layer 0 (fused gather+GEMM+LN+ReLU) ----
    if (fan0 == 15)
        fused_sage<64, 15, float, false><<<(N1 + 63) / 64, 256, 0, stream>>>(
            x_feat, e0src, tlid0, Wf0, b0, g0, be0, H0, N1, fan0,
            nullptr, nullptr, nullptr, 0);
    else
        fused_sage<64, 0, float, false><<<(N1 + 63) / 64, 256, 0, stream>>>(
            x_feat, e0src, tlid0, Wf0, b0, g0, be0, H0, N1, fan0,
            nullptr, nullptr, nullptr, 0);

    // ---- Layer 1 (fused, FC merged) ----
    if (fan1 == 10)
        fused_sage<32, 10, ushort, true><<<(N2 + 31) / 32, 256, 0, stream>>>(
            H0, e1src, tlid1, Wf1, b1, g1, be1, nullptr, N2, fan1,
            Wfc, fcb, (float*)d_out, C);
    else
        fused_sage<32, 0, ushort, true><<<(N2 + 31) / 32, 256, 0, stream>>>(
            H0, e1src, tlid1, Wf1, b1, g1, be1, nullptr, N2, fan1,
            Wfc, fcb, (float*)d_out, C);
}